// Round 1
// baseline (351.927 us; speedup 1.0000x reference)
//
#include <hip/hip_runtime.h>

// BaggingMaxPool: out[d] = mean_k( max_{r in indices[k,:]} inp[r][d] )
// N=1024 rows, D=100000 cols, K=20 rounds, SELECT_N=256.
//
// Strategy: single streaming pass over inp (410 MB). Per-row 20-bit round-
// membership mask built in LDS per block from indices (20 KB, L3-resident).
// Mask is wave-uniform per row -> readfirstlane -> scalar branches, so each
// element costs only popcount(mask) ~ 4.4 v_max ops instead of 20.
// VEC=4 columns/thread (float4 loads, 16B/lane), manual 2-stage register
// pipeline of 8-row tiles to keep ~8-16 loads in flight per thread.

#define N_ROWS   1024
#define D_COLS   100000
#define K_ROUNDS 20
#define SEL_N    256
#define NIDX     (K_ROUNDS * SEL_N)   // 5120
#define VEC      4
#define NTHREADS (D_COLS / VEC)       // 25000
#define BLOCK    64
#define TILE     8

__device__ __forceinline__ void load_tile(float4 (&v)[TILE], const float* __restrict__ p, int r0) {
    #pragma unroll
    for (int j = 0; j < TILE; ++j) {
        v[j] = *reinterpret_cast<const float4*>(p + (size_t)(r0 + j) * D_COLS);
    }
}

__device__ __forceinline__ void process_tile(const float4 (&v)[TILE], int r0,
                                             const unsigned int* smask,
                                             float4 (&acc)[K_ROUNDS]) {
    #pragma unroll
    for (int j = 0; j < TILE; ++j) {
        unsigned int m = (unsigned int)__builtin_amdgcn_readfirstlane((int)smask[r0 + j]);
        #pragma unroll
        for (int k = 0; k < K_ROUNDS; ++k) {
            if (m & (1u << k)) {
                acc[k].x = fmaxf(acc[k].x, v[j].x);
                acc[k].y = fmaxf(acc[k].y, v[j].y);
                acc[k].z = fmaxf(acc[k].z, v[j].z);
                acc[k].w = fmaxf(acc[k].w, v[j].w);
            }
        }
    }
}

__global__ __launch_bounds__(BLOCK) void bagmax_kernel(
    const float* __restrict__ inp,
    const int*   __restrict__ indices,
    float*       __restrict__ out)
{
    __shared__ unsigned int smask[N_ROWS];
    const int tid = threadIdx.x;  // 0..63

    // --- build per-row round-membership mask in LDS (per block; 20KB idx reads hit L2/L3) ---
    #pragma unroll
    for (int i = tid; i < N_ROWS; i += BLOCK) smask[i] = 0u;
    __syncthreads();
    for (int i = tid; i < NIDX; i += BLOCK) {
        int r = indices[i];
        int k = i >> 8;              // i / SEL_N
        atomicOr(&smask[r], 1u << k);
    }
    __syncthreads();

    const int t = blockIdx.x * BLOCK + tid;
    if (t >= NTHREADS) return;       // no __syncthreads after this point
    const int col = t * VEC;
    const float* p = inp + col;

    float4 acc[K_ROUNDS];
    #pragma unroll
    for (int k = 0; k < K_ROUNDS; ++k)
        acc[k] = make_float4(-3.402823466e+38f, -3.402823466e+38f,
                             -3.402823466e+38f, -3.402823466e+38f);

    // --- streaming pass over all 1024 rows, software-pipelined in 8-row tiles ---
    float4 va[TILE], vb[TILE];
    load_tile(va, p, 0);
    #pragma unroll 1
    for (int r0 = 0; r0 < N_ROWS; r0 += 2 * TILE) {
        load_tile(vb, p, r0 + TILE);
        process_tile(va, r0, smask, acc);
        if (r0 + 2 * TILE < N_ROWS) load_tile(va, p, r0 + 2 * TILE);
        process_tile(vb, r0 + TILE, smask, acc);
    }

    // --- mean over rounds ---
    float4 s = make_float4(0.f, 0.f, 0.f, 0.f);
    #pragma unroll
    for (int k = 0; k < K_ROUNDS; ++k) {
        s.x += acc[k].x; s.y += acc[k].y; s.z += acc[k].z; s.w += acc[k].w;
    }
    const float inv = 1.0f / (float)K_ROUNDS;
    s.x *= inv; s.y *= inv; s.z *= inv; s.w *= inv;
    *reinterpret_cast<float4*>(out + col) = s;
}

extern "C" void kernel_launch(void* const* d_in, const int* in_sizes, int n_in,
                              void* d_out, int out_size, void* d_ws, size_t ws_size,
                              hipStream_t stream) {
    const float* inp     = (const float*)d_in[0];
    const int*   indices = (const int*)d_in[1];
    float*       out     = (float*)d_out;

    const int grid = (NTHREADS + BLOCK - 1) / BLOCK;  // 391
    bagmax_kernel<<<grid, BLOCK, 0, stream>>>(inp, indices, out);
}

// Round 2
// 335.068 us; speedup vs baseline: 1.0503x; 1.0503x over previous
//
#include <hip/hip_runtime.h>

// BaggingMaxPool: out[d] = mean_k( max_{r in indices[k,:]} inp[r][d] )
// N=1024 rows, D=100000 cols, K=20 rounds, SELECT_N=256.
//
// Single streaming pass over inp (410 MB). Per-row 20-bit round-membership
// mask in LDS (wave-uniform per row -> readfirstlane -> uniform scalar
// branches; avg popcount ~4.4 of 20 rounds taken per row).
//
// VEC=2 (float2) so acc[20] = 40 VGPRs + 2x8x2 = 32 tile VGPRs -> NO SPILL
// (round-1 kernel spilled: acc[20] float4 = 80 VGPRs vs 76 allocated).
// 782 blocks = ~3 waves/CU; 8 outstanding 8B loads/thread ~ 12KB/CU in
// flight >= BW-delay product.

#define N_ROWS   1024
#define D_COLS   100000
#define K_ROUNDS 20
#define SEL_N    256
#define NIDX     (K_ROUNDS * SEL_N)   // 5120
#define VEC      2
#define NTHREADS (D_COLS / VEC)       // 50000
#define BLOCK    64
#define TILE     8

__device__ __forceinline__ void load_tile(float2 (&v)[TILE], const float* __restrict__ p, int r0) {
    #pragma unroll
    for (int j = 0; j < TILE; ++j) {
        v[j] = *reinterpret_cast<const float2*>(p + (size_t)(r0 + j) * D_COLS);
    }
}

__device__ __forceinline__ void process_tile(const float2 (&v)[TILE], int r0,
                                             const unsigned int* smask,
                                             float2 (&acc)[K_ROUNDS]) {
    #pragma unroll
    for (int j = 0; j < TILE; ++j) {
        unsigned int m = (unsigned int)__builtin_amdgcn_readfirstlane((int)smask[r0 + j]);
        #pragma unroll
        for (int k = 0; k < K_ROUNDS; ++k) {
            if (m & (1u << k)) {
                acc[k].x = fmaxf(acc[k].x, v[j].x);
                acc[k].y = fmaxf(acc[k].y, v[j].y);
            }
        }
    }
}

__global__ __launch_bounds__(BLOCK) void bagmax_kernel(
    const float* __restrict__ inp,
    const int*   __restrict__ indices,
    float*       __restrict__ out)
{
    __shared__ unsigned int smask[N_ROWS];
    const int tid = threadIdx.x;  // 0..63

    // --- build per-row round-membership mask in LDS (idx reads are L2/L3-hot) ---
    #pragma unroll
    for (int i = tid; i < N_ROWS; i += BLOCK) smask[i] = 0u;
    __syncthreads();
    for (int i = tid; i < NIDX; i += BLOCK) {
        int r = indices[i];
        int k = i >> 8;              // i / SEL_N
        atomicOr(&smask[r], 1u << k);
    }
    __syncthreads();

    const int t = blockIdx.x * BLOCK + tid;
    if (t >= NTHREADS) return;       // no __syncthreads after this point
    const int col = t * VEC;
    const float* p = inp + col;

    float2 acc[K_ROUNDS];
    #pragma unroll
    for (int k = 0; k < K_ROUNDS; ++k)
        acc[k] = make_float2(-3.402823466e+38f, -3.402823466e+38f);

    // --- streaming pass over all 1024 rows, software-pipelined in 8-row tiles ---
    float2 va[TILE], vb[TILE];
    load_tile(va, p, 0);
    #pragma unroll 1
    for (int r0 = 0; r0 < N_ROWS; r0 += 2 * TILE) {
        load_tile(vb, p, r0 + TILE);
        process_tile(va, r0, smask, acc);
        if (r0 + 2 * TILE < N_ROWS) load_tile(va, p, r0 + 2 * TILE);
        process_tile(vb, r0 + TILE, smask, acc);
    }

    // --- mean over rounds ---
    float2 s = make_float2(0.f, 0.f);
    #pragma unroll
    for (int k = 0; k < K_ROUNDS; ++k) {
        s.x += acc[k].x; s.y += acc[k].y;
    }
    const float inv = 1.0f / (float)K_ROUNDS;
    s.x *= inv; s.y *= inv;
    *reinterpret_cast<float2*>(out + col) = s;
}

extern "C" void kernel_launch(void* const* d_in, const int* in_sizes, int n_in,
                              void* d_out, int out_size, void* d_ws, size_t ws_size,
                              hipStream_t stream) {
    const float* inp     = (const float*)d_in[0];
    const int*   indices = (const int*)d_in[1];
    float*       out     = (float*)d_out;

    const int grid = (NTHREADS + BLOCK - 1) / BLOCK;  // 782
    bagmax_kernel<<<grid, BLOCK, 0, stream>>>(inp, indices, out);
}